// Round 4
// baseline (289.773 us; speedup 1.0000x reference)
//
#include <hip/hip_runtime.h>
#include <hip/hip_bf16.h>
#include <math.h>

#define N_NODES 10000
#define N_EDGES 160000
#define SO_BLK 157          // ceil(10000/64) s-GEMM blocks
#define VO_BLK 469          // ceil(30000/64) v-GEMM blocks

typedef __attribute__((ext_vector_type(8))) short short8x;
typedef __attribute__((ext_vector_type(4))) float floatx4;
typedef __attribute__((ext_vector_type(4))) unsigned int uint4x;
typedef __attribute__((ext_vector_type(2))) unsigned int uint2x;

union S8 { short8x v; unsigned short u[8]; uint4 q; uint4x qx; };
union U2 { uint2x v; unsigned short us[4]; };

__device__ __forceinline__ unsigned short f2bf(float x) {
    unsigned int u = __float_as_uint(x);
    return (unsigned short)((u + 0x7fffu + ((u >> 16) & 1u)) >> 16);
}
__device__ __forceinline__ float bf2f(unsigned short u) {
    return __uint_as_float(((unsigned)u) << 16);
}
__device__ __forceinline__ float silu_c(float x) {
    return 1.679f * x / (1.0f + __expf(-x));
}

// ---------------- pack_all: all weight pre-packs in one launch ----------------
// blocks [0,192): b_pre; [192,208): w2a; [208,210): w1a; [210,226): b_lin
__global__ __launch_bounds__(256) void pack_all_kernel(
    const float* __restrict__ sc_ws, const float* __restrict__ lin2_ws,
    const float* __restrict__ sc_wv, const float* __restrict__ lin2_wv,
    const float* __restrict__ fc_w2, const float* __restrict__ fc_w1,
    const float* __restrict__ lin1_ws, const float* __restrict__ lin1_wv,
    unsigned short* __restrict__ b_pre, unsigned short* __restrict__ w2a,
    unsigned short* __restrict__ w1a, unsigned short* __restrict__ b_lin)
{
    const int bid = blockIdx.x;
    const int t = threadIdx.x;
    if (bid < 192) {
        int id = bid * 256 + t;                  // 0..49151
        int mat = id / 24576;
        int slot = id - mat * 24576;
        int ks = slot >> 9;
        int rr = slot & 511;
        int lane = rr & 63;
        int quad = lane >> 4;
        int n = ((rr >> 6) << 4) + (lane & 15);
        const float* sc  = mat ? sc_wv  : sc_ws;
        const float* lin = mat ? lin2_wv : lin2_ws;
        S8 pk;
        #pragma unroll
        for (int j = 0; j < 8; j++) {
            int k = ks * 32 + quad * 8 + j;
            float w;
            if (k < 1280) {
                int u = k & 127, v = k >> 7;
                w = sc[(u * 10 + v) * 128 + n];
            } else {
                w = lin[(k - 1280) * 128 + n];
            }
            pk.u[j] = f2bf(w);
        }
        *(uint4*)(b_pre + (size_t)id * 8) = pk.q;
    } else if (bid < 208) {
        int id = (bid - 192) * 256 + t;          // 0..4095
        int lane = id & 63;
        int mfg = (id >> 6) & 31;
        int ks = id >> 11;
        int col = mfg * 16 + (lane & 15);
        int k0 = ks * 32 + (lane >> 4) * 8;
        S8 pk;
        #pragma unroll
        for (int j = 0; j < 8; j++)
            pk.u[j] = f2bf(fc_w2[(k0 + j) * 512 + col] * 0.125f);
        *(uint4*)(w2a + (size_t)id * 8) = pk.q;
    } else if (bid < 210) {
        int id = (bid - 208) * 256 + t;          // 0..511
        int lane = id & 63;
        int mf = (id >> 6) & 3;
        int ks = id >> 8;
        int m = mf * 16 + (lane & 15);
        int k0 = ks * 32 + (lane >> 4) * 8;
        S8 pk;
        #pragma unroll
        for (int j = 0; j < 8; j++)
            pk.u[j] = f2bf(fc_w1[(k0 + j) * 64 + m] * 0.125f);
        *(uint4*)(w1a + (size_t)id * 8) = pk.q;
    } else {
        int id = (bid - 210) * 256 + t;          // 0..4095
        int mat = id >> 11;
        int slot = id & 2047;
        int ks = slot >> 9;
        int rr = slot & 511;
        int nf = rr >> 6;
        int lane = rr & 63;
        int n = nf * 16 + (lane & 15);
        int k0 = ks * 32 + (lane >> 4) * 8;
        const float* w = mat ? lin1_wv : lin1_ws;
        const float l1 = 0.0883883476483f;
        S8 pk;
        #pragma unroll
        for (int j = 0; j < 8; j++)
            pk.u[j] = f2bf(w[(k0 + j) * 128 + n] * l1);
        *(uint4*)(b_lin + (size_t)id * 8) = pk.q;
    }
}

// ---------------- Kernel A: lin1 via MFMA -> packed bf16 y + bf16 xvP ----------------
__global__ __launch_bounds__(256) void node_lin1_mfma(
    const float* __restrict__ node_feats,
    const unsigned short* __restrict__ b_lin,
    unsigned short* __restrict__ y_pk,
    unsigned short* __restrict__ xvP16)
{
    __shared__ __align__(16) unsigned char smem[32768];
    short8x* Al = (short8x*)smem;
    unsigned short* Yt = (unsigned short*)smem;

    const int blk = blockIdx.x;   // 313
    const int t = threadIdx.x;
    const int base = blk * 32;
    const int lane = t & 63;
    const int wv = t >> 6;
    const int m15 = lane & 15;
    const int k0q = (lane >> 4) * 8;

    #pragma unroll
    for (int it = 0; it < 8; it++) {
        int g = wv * 8 + it;
        int af = g >> 2;
        int ks = g & 3;
        int m = af * 16 + m15;
        int comp = m >> 5;
        int nloc = m & 31;
        int node = base + nloc;
        int valid = (node < N_NODES);
        if (!valid) node = N_NODES - 1;
        int k0 = ks * 32 + k0q;
        const float* row = node_feats + (size_t)node * 512;
        S8 pk;
        if (comp == 0) {
            float4 a = *(const float4*)&row[k0];
            float4 b = *(const float4*)&row[k0 + 4];
            pk.u[0] = f2bf(a.x); pk.u[1] = f2bf(a.y); pk.u[2] = f2bf(a.z); pk.u[3] = f2bf(a.w);
            pk.u[4] = f2bf(b.x); pk.u[5] = f2bf(b.y); pk.u[6] = f2bf(b.z); pk.u[7] = f2bf(b.w);
        } else {
            int c = comp - 1;
            #pragma unroll
            for (int j = 0; j < 8; j++)
                pk.u[j] = f2bf(row[128 + (k0 + j) * 3 + c]);
            if (valid)
                *(uint4*)&xvP16[((size_t)node * 3 + c) * 128 + k0] = pk.q;
        }
        Al[(ks * 8 + af) * 64 + lane] = pk.v;
    }
    __syncthreads();

    floatx4 c[8][2];
    #pragma unroll
    for (int af = 0; af < 8; af++) {
        c[af][0] = (floatx4){0.f, 0.f, 0.f, 0.f};
        c[af][1] = (floatx4){0.f, 0.f, 0.f, 0.f};
    }

    const uint4* bq = (const uint4*)b_lin;
    #pragma unroll
    for (int ks = 0; ks < 4; ks++) {
        S8 bs0, bs1, bv0, bv1;
        bs0.q = bq[       ks*512 + (wv*2+0)*64 + lane];
        bs1.q = bq[       ks*512 + (wv*2+1)*64 + lane];
        bv0.q = bq[2048 + ks*512 + (wv*2+0)*64 + lane];
        bv1.q = bq[2048 + ks*512 + (wv*2+1)*64 + lane];
        #pragma unroll
        for (int af = 0; af < 8; af++) {
            short8x a = Al[(ks*8 + af)*64 + lane];
            if (af < 2) {
                c[af][0] = __builtin_amdgcn_mfma_f32_16x16x32_bf16(a, bs0.v, c[af][0], 0, 0, 0);
                c[af][1] = __builtin_amdgcn_mfma_f32_16x16x32_bf16(a, bs1.v, c[af][1], 0, 0, 0);
            } else {
                c[af][0] = __builtin_amdgcn_mfma_f32_16x16x32_bf16(a, bv0.v, c[af][0], 0, 0, 0);
                c[af][1] = __builtin_amdgcn_mfma_f32_16x16x32_bf16(a, bv1.v, c[af][1], 0, 0, 0);
            }
        }
    }
    __syncthreads();

    {
        const int rq = (lane >> 4) * 4;
        #pragma unroll
        for (int af = 0; af < 8; af++) {
            #pragma unroll
            for (int nf = 0; nf < 2; nf++) {
                int u = wv * 32 + nf * 16 + m15;
                #pragma unroll
                for (int i = 0; i < 4; i++) {
                    int m = af * 16 + rq + i;
                    int comp = m >> 5, nloc = m & 31;
                    Yt[(nloc * 128 + u) * 4 + comp] = f2bf(c[af][nf][i]);
                }
            }
        }
    }
    __syncthreads();
    {
        unsigned short* dst = y_pk + (size_t)base * 512;
        int nrem = N_NODES - base;
        #pragma unroll
        for (int it = 0; it < 8; it++) {
            int idx = it * 256 + t;
            if ((idx >> 6) < nrem)
                *(uint4*)(dst + (size_t)idx * 8) = *(const uint4*)&Yt[idx * 8];
        }
    }
}

// ---------------- CSR build ----------------
__global__ __launch_bounds__(256) void hist_kernel(const int* __restrict__ edge_index,
                                                   int* __restrict__ deg) {
    int e = blockIdx.x * 256 + threadIdx.x;
    if (e < N_EDGES) atomicAdd(&deg[edge_index[e]], 1);
}

__global__ __launch_bounds__(1024) void scan_kernel(const int* __restrict__ deg,
                                                    int* __restrict__ row_start,
                                                    int* __restrict__ cursor) {
    __shared__ int wsum[16];
    __shared__ int carry_s;
    const int t = threadIdx.x;
    const int lane = t & 63, w = t >> 6;
    if (t == 0) carry_s = 0;
    __syncthreads();
    for (int chunk = 0; chunk < 10; chunk++) {
        int idx = chunk * 1024 + t;
        int v = (idx < N_NODES) ? deg[idx] : 0;
        int x = v;
        #pragma unroll
        for (int off = 1; off < 64; off <<= 1) {
            int yv = __shfl_up(x, off, 64);
            if (lane >= off) x += yv;
        }
        if (lane == 63) wsum[w] = x;
        __syncthreads();
        int wpre = 0;
        for (int i = 0; i < w; i++) wpre += wsum[i];
        int incl = x + wpre + carry_s;
        int excl = incl - v;
        if (idx < N_NODES) { row_start[idx] = excl; cursor[idx] = excl; }
        __syncthreads();
        if (t == 1023) carry_s = incl;
        __syncthreads();
    }
    if (t == 0) row_start[N_NODES] = carry_s;
}

__global__ __launch_bounds__(256) void scatter_kernel(const int* __restrict__ edge_index,
                                                      const float* __restrict__ edge_attrs,
                                                      int* __restrict__ cursor,
                                                      int* __restrict__ edge_list,
                                                      int* __restrict__ srcs,
                                                      int* __restrict__ dsts,
                                                      float* __restrict__ ea_sorted) {
    int e = blockIdx.x * 256 + threadIdx.x;
    if (e < N_EDGES) {
        int dd = edge_index[e];
        int pos = atomicAdd(&cursor[dd], 1);
        edge_list[pos] = e;
        srcs[pos] = edge_index[N_EDGES + e];
        dsts[pos] = dd;
        float4 ea = *(const float4*)(edge_attrs + (size_t)e * 4);
        *(float4*)(ea_sorted + (size_t)pos * 4) = ea;
    }
}

// ---------------- Kernel B1: edge MLP (sorted order) -> packed bf16 w ----------------
// w_pk[pos][u][4] = bf16{ss, sv, vs, vv}
// LDS 26.4 KB -> 6 blocks/CU; phase 3 in 4 passes of 2 m-frags (32 acc VGPRs)
__global__ __launch_bounds__(256) void edge_w_mfma(
    const float* __restrict__ edge_feats,
    const int* __restrict__ edge_list,
    const float* __restrict__ fc_w0,
    const unsigned short* __restrict__ w1a,
    const unsigned short* __restrict__ w2a,
    unsigned short* __restrict__ w_pk)
{
    __shared__ __align__(16) unsigned char smem[26368];
    float* ef = (float*)smem;                               // [0, 2304)
    unsigned short* h0b = (unsigned short*)(smem + 2304);   // [2304, 11520): 64 x 72
    unsigned short* T   = (unsigned short*)smem;            // [0, 16896): 64 x 132 (epilogue)
    unsigned short* h1b = (unsigned short*)(smem + 16896);  // [16896, 26112): 64 x 72
    int* eids = (int*)(smem + 26112);                       // [26112, 26368)

    const int blk = blockIdx.x;      // 2500
    const int t = threadIdx.x;
    const int eb0 = blk * 64;
    const int lane = t & 63;
    const int wv = t >> 6;
    const int quad = lane >> 4;
    const int m15 = lane & 15;

    if (t < 64) eids[t] = edge_list[eb0 + t];
    __syncthreads();

    #pragma unroll
    for (int r = 0; r < 2; r++) {
        int idx = r * 256 + t;
        int el = idx >> 3;
        int k = idx & 7;
        ef[el * 9 + k] = edge_feats[(size_t)eids[el] * 8 + k];
    }
    __syncthreads();

    // phase 1 (VALU, f32): h0 = silu_c(ef @ w0 / sqrt(8)) -> bf16
    {
        const int e_loc = t >> 2;
        const int c0 = (t & 3) * 16;
        float a0[16];
        #pragma unroll
        for (int i = 0; i < 16; i++) a0[i] = 0.f;
        const float* efr = &ef[e_loc * 9];
        #pragma unroll
        for (int k = 0; k < 8; k++) {
            float ek = efr[k];
            float w[16];
            #pragma unroll
            for (int q4 = 0; q4 < 4; q4++)
                *(float4*)&w[q4*4] = *(const float4*)&fc_w0[k*64 + c0 + q4*4];
            #pragma unroll
            for (int i = 0; i < 16; i++) a0[i] += ek * w[i];
        }
        const float is8 = 0.35355339059f;
        S8 p0, p1;
        #pragma unroll
        for (int i = 0; i < 8; i++) {
            p0.u[i] = f2bf(silu_c(a0[i] * is8));
            p1.u[i] = f2bf(silu_c(a0[8 + i] * is8));
        }
        *(uint4*)&h0b[e_loc * 72 + c0]     = p0.q;
        *(uint4*)&h0b[e_loc * 72 + c0 + 8] = p1.q;
    }
    __syncthreads();

    // phase 2 (MFMA): h1 = silu_c(h0 @ w1 / 8)
    {
        floatx4 c2[4];
        #pragma unroll
        for (int ee = 0; ee < 4; ee++) c2[ee] = (floatx4){0.f, 0.f, 0.f, 0.f};
        const uint4* w1aq = (const uint4*)w1a;
        #pragma unroll
        for (int ks = 0; ks < 2; ks++) {
            S8 afr;
            afr.q = w1aq[(ks*4 + wv)*64 + lane];
            #pragma unroll
            for (int ee = 0; ee < 4; ee++) {
                S8 bfr;
                bfr.q = *(const uint4*)&h0b[(ee*16 + m15) * 72 + ks*32 + quad*8];
                c2[ee] = __builtin_amdgcn_mfma_f32_16x16x32_bf16(afr.v, bfr.v, c2[ee], 0, 0, 0);
            }
        }
        #pragma unroll
        for (int ee = 0; ee < 4; ee++) {
            ushort4 pk = make_ushort4(f2bf(silu_c(c2[ee][0])), f2bf(silu_c(c2[ee][1])),
                                      f2bf(silu_c(c2[ee][2])), f2bf(silu_c(c2[ee][3])));
            *(ushort4*)&h1b[(ee*16 + m15) * 72 + wv*16 + quad*4] = pk;
        }
    }
    __syncthreads();

    // phase 3 (MFMA, 4 passes of 2 m-frags); pass p covers cols p*32..p*32+31 of comp wv
    const uint4* w2aq = (const uint4*)w2a;
    #pragma unroll 1
    for (int p = 0; p < 4; p++) {
        floatx4 c3[2][4];
        #pragma unroll
        for (int mf = 0; mf < 2; mf++)
            #pragma unroll
            for (int ee = 0; ee < 4; ee++)
                c3[mf][ee] = (floatx4){0.f, 0.f, 0.f, 0.f};

        #pragma unroll
        for (int ks = 0; ks < 2; ks++) {
            S8 bfr[4];
            #pragma unroll
            for (int ee = 0; ee < 4; ee++)
                bfr[ee].q = *(const uint4*)&h1b[(ee*16 + m15) * 72 + ks*32 + quad*8];
            #pragma unroll
            for (int mf = 0; mf < 2; mf++) {
                S8 afr;
                afr.q = w2aq[(size_t)(ks*32 + wv*8 + p*2 + mf) * 64 + lane];
                #pragma unroll
                for (int ee = 0; ee < 4; ee++)
                    c3[mf][ee] = __builtin_amdgcn_mfma_f32_16x16x32_bf16(afr.v, bfr[ee].v, c3[mf][ee], 0, 0, 0);
            }
        }

        __syncthreads();   // T region free (prev pass stores done / ef+h0b dead)
        // dump interleaved: T[e*132 + col'*4 + comp], comp = wv
        #pragma unroll
        for (int mf = 0; mf < 2; mf++) {
            #pragma unroll
            for (int ee = 0; ee < 4; ee++) {
                int e = ee*16 + m15;
                #pragma unroll
                for (int i = 0; i < 4; i++) {
                    int colp = mf*16 + quad*4 + i;
                    T[e*132 + colp*4 + wv] = f2bf(c3[mf][ee][i]);
                }
            }
        }
        __syncthreads();

        // coalesced store: uint2 per (e, cu); per e-row 256 B contiguous
        #pragma unroll
        for (int it = 0; it < 8; it++) {
            int idx = it * 256 + t;          // 0..2047
            int e  = idx >> 5;
            int cu = idx & 31;
            uint2x v = *(const uint2x*)&T[e*132 + cu*4];
            unsigned short* dstp = w_pk + ((size_t)(eb0 + e) * 128 + p*32 + cu) * 4;
            __builtin_nontemporal_store(v, (uint2x*)dstp);
        }
    }
}

// ---------------- Kernel B2: contiguous-edge streaming gather ----------------
// Each wave owns 2 consecutive nodes and streams their contiguous edge range.
// Lane handles 2 u-slots (16 B/edge loads). dst-change tracking with uniform
// flushes (plain coalesced stores, no atomics, no memset). Waves independent.
__global__ __launch_bounds__(256) void gather_kernel(
    const int* __restrict__ row_start,
    const int* __restrict__ srcs,
    const int* __restrict__ dsts,
    const float* __restrict__ ea_sorted,
    const unsigned short* __restrict__ w_pk,
    const unsigned short* __restrict__ y_pk,
    float* __restrict__ accS,
    float* __restrict__ accV)
{
    const int t = threadIdx.x;
    const int wv = t >> 6;
    const int lane = t & 63;
    const int u0 = lane << 1;                  // u0, u0+1
    int cur = blockIdx.x * 8 + wv * 2;         // grid 1250 x 8 nodes = 10000 exact
    const int nb_end = cur + 2;

    const int eb = row_start[cur];
    const int ee = row_start[nb_end];

    float aS0a=0.f,aS0b=0.f, aS1a=0.f,aS1b=0.f;
    float aV2ax=0.f,aV2ay=0.f,aV2az=0.f, aV2bx=0.f,aV2by=0.f,aV2bz=0.f;
    float aV3ax=0.f,aV3ay=0.f,aV3az=0.f, aV3bx=0.f,aV3by=0.f,aV3bz=0.f;

    const float inv = 0.25f;                   // 1/sqrt(16)
    const float s1c = 0.57735026919f * 0.25f;

    auto flush = [&](int n) {
        *(float2*)(accS + (size_t)n*256 + u0)        = make_float2(aS0a*inv, aS0b*inv);
        *(float2*)(accS + (size_t)n*256 + 128 + u0)  = make_float2(aS1a*s1c, aS1b*s1c);
        *(float2*)(accV + ((size_t)n*3+0)*256 + u0)       = make_float2(aV2ax*inv, aV2bx*inv);
        *(float2*)(accV + ((size_t)n*3+0)*256 + 128 + u0) = make_float2(aV3ax*inv, aV3bx*inv);
        *(float2*)(accV + ((size_t)n*3+1)*256 + u0)       = make_float2(aV2ay*inv, aV2by*inv);
        *(float2*)(accV + ((size_t)n*3+1)*256 + 128 + u0) = make_float2(aV3ay*inv, aV3by*inv);
        *(float2*)(accV + ((size_t)n*3+2)*256 + u0)       = make_float2(aV2az*inv, aV2bz*inv);
        *(float2*)(accV + ((size_t)n*3+2)*256 + 128 + u0) = make_float2(aV3az*inv, aV3bz*inv);
        aS0a=aS0b=aS1a=aS1b=0.f;
        aV2ax=aV2ay=aV2az=aV2bx=aV2by=aV2bz=0.f;
        aV3ax=aV3ay=aV3az=aV3bx=aV3by=aV3bz=0.f;
    };

    auto consume = [&](const S8& w8, const S8& y8, const float4& ea) {
        // u0 slot
        {
            float wss = bf2f(w8.u[0]), wsv = bf2f(w8.u[1]);
            float wvs = bf2f(w8.u[2]), wvv = bf2f(w8.u[3]);
            float qs = bf2f(y8.u[0]), q0 = bf2f(y8.u[1]), q1 = bf2f(y8.u[2]), q2 = bf2f(y8.u[3]);
            aS0a += wss * qs * ea.x;
            aS1a += wvv * (q0*ea.y + q1*ea.z + q2*ea.w);
            float tsv = wsv * qs;
            aV2ax += tsv * ea.y; aV2ay += tsv * ea.z; aV2az += tsv * ea.w;
            float tvs = wvs * ea.x;
            aV3ax += tvs * q0; aV3ay += tvs * q1; aV3az += tvs * q2;
        }
        // u0+1 slot
        {
            float wss = bf2f(w8.u[4]), wsv = bf2f(w8.u[5]);
            float wvs = bf2f(w8.u[6]), wvv = bf2f(w8.u[7]);
            float qs = bf2f(y8.u[4]), q0 = bf2f(y8.u[5]), q1 = bf2f(y8.u[6]), q2 = bf2f(y8.u[7]);
            aS0b += wss * qs * ea.x;
            aS1b += wvv * (q0*ea.y + q1*ea.z + q2*ea.w);
            float tsv = wsv * qs;
            aV2bx += tsv * ea.y; aV2by += tsv * ea.z; aV2bz += tsv * ea.w;
            float tvs = wvs * ea.x;
            aV3bx += tvs * q0; aV3by += tvs * q1; aV3bz += tvs * q2;
        }
    };

    if (eb < ee) {
        const int last = N_EDGES - 1;
        int jB0 = (eb+1 < last) ? eb+1 : last;
        int j2  = (eb+2 < last) ? eb+2 : last;
        int j3  = (eb+3 < last) ? eb+3 : last;

        int sA = srcs[eb],  dA = dsts[eb];
        int sB = srcs[jB0], dB = dsts[jB0];
        int sP0 = srcs[j2], dP0 = dsts[j2];
        int sP1 = srcs[j3], dP1 = dsts[j3];

        S8 wA, wB, yA, yB; float4 eaA, eaB;
        wA.qx = __builtin_nontemporal_load((const uint4x*)(w_pk + ((size_t)eb * 128 + u0) * 4));
        eaA  = *(const float4*)(ea_sorted + (size_t)eb * 4);
        yA.q = *(const uint4*)(y_pk + ((size_t)sA * 128 + u0) * 4);
        wB.qx = __builtin_nontemporal_load((const uint4x*)(w_pk + ((size_t)jB0 * 128 + u0) * 4));
        eaB  = *(const float4*)(ea_sorted + (size_t)jB0 * 4);
        yB.q = *(const uint4*)(y_pk + ((size_t)sB * 128 + u0) * 4);

        for (int i = eb; i < ee; i += 2) {
            // ---- consume A (edge i, always valid) ----
            while (cur < dA) flush(cur++);
            consume(wA, yA, eaA);
            // ---- refill A <- edge i+2 ----
            {
                int jn = (i+2 < last) ? i+2 : last;
                wA.qx = __builtin_nontemporal_load((const uint4x*)(w_pk + ((size_t)jn * 128 + u0) * 4));
                eaA  = *(const float4*)(ea_sorted + (size_t)jn * 4);
                yA.q = *(const uint4*)(y_pk + ((size_t)sP0 * 128 + u0) * 4);
                dA = dP0;
                int j4 = (i+4 < last) ? i+4 : last;
                sP0 = srcs[j4]; dP0 = dsts[j4];
            }
            // ---- consume B (edge i+1, guarded; branch is wave-uniform) ----
            if (i + 1 < ee) {
                while (cur < dB) flush(cur++);
                consume(wB, yB, eaB);
            }
            // ---- refill B <- edge i+3 ----
            {
                int jn = (i+3 < last) ? i+3 : last;
                wB.qx = __builtin_nontemporal_load((const uint4x*)(w_pk + ((size_t)jn * 128 + u0) * 4));
                eaB  = *(const float4*)(ea_sorted + (size_t)jn * 4);
                yB.q = *(const uint4*)(y_pk + ((size_t)sP1 * 128 + u0) * 4);
                dB = dP1;
                int j5 = (i+5 < last) ? i+5 : last;
                sP1 = srcs[j5]; dP1 = dsts[j5];
            }
        }
    }
    while (cur < nb_end) flush(cur++);
}

// ---------------- node_out as MFMA GEMM, latency-pipelined ----------------
// 64-row tiles (grid 626 = 2.45 blocks/CU), one A-slot per thread (conflict-free
// LDS), sc-part A preloaded in registers (4 chunks x 8), depth-2 B / tail-acc
// register prefetch, one raw s_barrier per K-step (lgkmcnt-only drain so B
// prefetch stays in flight across barriers).
__global__ __launch_bounds__(256) void node_out_mfma(
    const float* __restrict__ node_feats,
    const float* __restrict__ node_attrs,
    const unsigned short* __restrict__ xvP16,
    const float* __restrict__ accS,
    const float* __restrict__ accV,
    const unsigned short* __restrict__ b_pre,
    float* __restrict__ out)
{
    __shared__ __align__(16) short8x Abuf[2][256];   // 2 x 4 KB double buffer
    const int bid = blockIdx.x;
    const int t = threadIdx.x;
    const int lane = t & 63;
    const int wv = t >> 6;
    const bool is_s = (bid < SO_BLK);

    // this thread's A slot: row r (0..63), k-quad (0..3); slot index == t
    const int r    = ((t >> 6) << 4) + (t & 15);
    const int q8   = ((t >> 4) & 3) * 8;

    const float* px = nullptr;
    const unsigned short* pxv = nullptr;
    const float* pa;
    const float* pat;
    if (is_s) {
        int R = bid * 64 + r;
        int node = (R < N_NODES) ? R : 0;
        px  = node_feats + (size_t)node * 512;
        pa  = accS + (size_t)node * 256;
        pat = node_attrs + node * 10;
    } else {
        int Rg = (bid - SO_BLK) * 64 + r;
        if (Rg >= 3 * N_NODES) Rg = 0;
        int node = Rg / 3;
        pxv = xvP16 + (size_t)Rg * 128;
        pa  = accV + (size_t)Rg * 256;
        pat = node_attrs + node * 10;
    }

    const uint4* bb = (const uint4*)(b_pre) + (is_s ? 0 : 24576);
    const float sc_norm = 0.02795084972f;   // 1/sqrt(1280)
    const float l2 = 0.0625f;               // 1/sqrt(256)

    // ---- preload the 4 sc-part A chunks for this (row, quad) ----
    float xf[4][8];
    S8    xh[4];
    if (is_s) {
        #pragma unroll
        for (int c = 0; c < 4; c++) {
            floatx4 lo = *(const floatx4*)&px[c*32 + q8];
            floatx4 hi = *(const floatx4*)&px[c*32 + q8 + 4];
            #pragma unroll
            for (int i = 0; i < 4; i++) { xf[c][i] = lo[i]; xf[c][4+i] = hi[i]; }
        }
    } else {
        #pragma unroll
        for (int c = 0; c < 4; c++)
            xh[c].q = *(const uint4*)&pxv[c*32 + q8];
    }
    float attC = pat[0] * sc_norm;

    floatx4 acc[4][2];
    #pragma unroll
    for (int af = 0; af < 4; af++) {
        acc[af][0] = (floatx4){0.f, 0.f, 0.f, 0.f};
        acc[af][1] = (floatx4){0.f, 0.f, 0.f, 0.f};
    }

    const int cof0 = (wv*2+0)*64 + lane;
    const int cof1 = (wv*2+1)*64 + lane;

    auto packx = [&](int c_, float att_) -> short8x {
        S8 pk;
        if (is_s) {
            #pragma unroll
            for (int i = 0; i < 8; i++) pk.u[i] = f2bf(xf[c_][i] * att_);
        } else {
            #pragma unroll
            for (int i = 0; i < 8; i++) pk.u[i] = f2bf(bf2f(xh[c_].u[i]) * att_);
        }
        return pk.v;
    };
    auto mstep = [&](int kb, const S8& b0, const S8& b1) {
        __builtin_amdgcn_s_setprio(1);
        #pragma unroll
        for (int af = 0; af < 4; af++) {
            short8x a = Abuf[kb][af*64 + lane];
            acc[af][0] = __builtin_amdgcn_mfma_f32_16x16x32_bf16(a, b0.v, acc[af][0], 0, 0, 0);
            acc[af][1] = __builtin_amdgcn_mfma_f32_16x16x32_bf16(a, b1.v, acc[af][1], 0, 0, 0);
        }
        __builtin_amdgcn_s_setprio(0);
    };
    auto bload = [&](int k2, S8& b0, S8& b1) {
        b0.q = bb[(size_t)k2*512 + cof0];
        b1.q = bb[(size_t)k2*512 + cof1];
    };
    auto barrier_ = [&]() {
        asm volatile("s_waitcnt lgkmcnt(0)" ::: "memory");
        __builtin_amdgcn_s_barrier();
    };

    // B prefetch (depth 2)
    S8 bA0, bA1, bB0, bB1;
    bload(0, bA0, bA1);
    bload(1, bB0, bB1);

    // prologue: A(0) -> buf0
    Abuf[0][t] = packx(0, attC);
    barrier_();

    // ---- main loop: ks = 0..35 (vblk 0..8), A from preloaded chunks ----
    #pragma unroll 1
    for (int vb = 0; vb < 9; vb++) {
        float attN = pat[vb + 1] * sc_norm;
        const int ksb = vb * 4;
        Abuf[1][t] = packx(1, attC); mstep(0, bA0, bA1); bload(ksb+2, bA0, bA1); barrier_();
        Abuf[0][t] = packx(2, attC); mstep(1, bB0, bB1); bload(ksb+3, bB0, bB1); barrier_();
        Abuf[1][t] = packx(3, attC); mstep(0, bA0, bA1); bload(ksb+4, bA0, bA1); barrier_();
        Abuf[0][t] = packx(0, attN); mstep(1, bB0, bB1); bload(ksb+5, bB0, bB1); barrier_();
        attC = attN;
    }

    // ---- ks = 36..47 explicit (attC == pat[9]); tail A from acc (depth-2) ----
    floatx4 aT0[2], aT1[2];
    auto issue0 = [&](int k_) { int j2 = (k_-40)*32 + q8;
        aT0[0] = *(const floatx4*)&pa[j2]; aT0[1] = *(const floatx4*)&pa[j2+4]; };
    auto issue1 = [&](int k_) { int j2 = (k_-40)*32 + q8;
        aT1[0] = *(const floatx4*)&pa[j2]; aT1[1] = *(const floatx4*)&pa[j2+4]; };
    auto packT = [&](const floatx4* a2) -> short8x {
        S8 pk;
        #pragma unroll
        for (int i = 0; i < 4; i++) { pk.u[i] = f2bf(a2[0][i] * l2); pk.u[4+i] = f2bf(a2[1][i] * l2); }
        return pk.v;
    };

    // ks=36
    Abuf[1][t] = packx(1, attC); mstep(0, bA0, bA1); bload(38, bA0, bA1); barrier_();
    // ks=37
    Abuf[0][t] = packx(2, attC); mstep(1, bB0, bB1); bload(39, bB0, bB1); barrier_();
    // ks=38
    issue0(40);
    Abuf[1][t] = packx(3, attC); mstep(0, bA0, bA1); bload(40, bA0, bA1); barrier_();
    // ks=39
    issue1(41);
    Abuf[0][t] = packT(aT0); mstep(1, bB0, bB1); bload(41, bB0, bB1); barrier_();
    // ks=40
    issue0(42);
    Abuf[1][t] = packT(aT1); mstep(0, bA0, bA1); bload(42, bA0, bA1); barrier_();
    // ks=41
    issue1(43);
    Abuf[0][t] = packT(aT0); mstep(1, bB0, bB1); bload(43, bB0, bB1); barrier_();
    // ks=42
    issue0(44);
    Abuf[1][t] = packT(aT1); mstep(0, bA0, bA1); bload(44, bA0, bA1); barrier_();
    // ks=43
    issue1(45);
    Abuf[0][t] = packT(aT0); mstep(1, bB0, bB1); bload(45, bB0, bB1); barrier_();
    // ks=44
    issue0(46);
    Abuf[1][t] = packT(aT1); mstep(0, bA0, bA1); bload(46, bA0, bA1); barrier_();
    // ks=45
    issue1(47);
    Abuf[0][t] = packT(aT0); mstep(1, bB0, bB1); bload(47, bB0, bB1); barrier_();
    // ks=46
    Abuf[1][t] = packT(aT1); mstep(0, bA0, bA1); barrier_();
    // ks=47
    mstep(1, bB0, bB1);

    // ---- epilogue ----
    const int m = lane & 15;
    const int rq = (lane >> 4) * 4;
    if (is_s) {
        const int n0 = bid * 64;
        #pragma unroll
        for (int af = 0; af < 4; af++) {
            #pragma unroll
            for (int i = 0; i < 4; i++) {
                int n = n0 + af*16 + rq + i;
                if (n < N_NODES) {
                    out[(size_t)n*512 + wv*32 + m]      = acc[af][0][i];
                    out[(size_t)n*512 + wv*32 + 16 + m] = acc[af][1][i];
                }
            }
        }
    } else {
        const int r0 = (bid - SO_BLK) * 64;
        #pragma unroll
        for (int af = 0; af < 4; af++) {
            #pragma unroll
            for (int i = 0; i < 4; i++) {
                int Rg = r0 + af*16 + rq + i;
                if (Rg < 3 * N_NODES) {
                    int nn = Rg / 3;
                    int cc = Rg - nn * 3;
                    float* po = out + (size_t)nn*512 + 128 + cc;
                    po[(wv*32 + m)*3]      = acc[af][0][i];
                    po[(wv*32 + 16 + m)*3] = acc[af][1][i];
                }
            }
        }
    }
}

extern "C" void kernel_launch(void* const* d_in, const int* in_sizes, int n_in,
                              void* d_out, int out_size, void* d_ws, size_t ws_size,
                              hipStream_t stream) {
    const float* node_feats = (const float*)d_in[0];
    const float* node_attrs = (const float*)d_in[1];
    const float* edge_feats = (const float*)d_in[2];
    const float* edge_attrs = (const float*)d_in[3];
    const int*   edge_index = (const int*)  d_in[4];
    const float* lin1_ws    = (const float*)d_in[5];
    const float* lin1_wv    = (const float*)d_in[6];
    const float* fc_w0      = (const float*)d_in[7];
    const float* fc_w1      = (const float*)d_in[8];
    const float* fc_w2      = (const float*)d_in[9];
    const float* lin2_ws    = (const float*)d_in[10];
    const float* lin2_wv    = (const float*)d_in[11];
    const float* sc_ws      = (const float*)d_in[12];
    const float* sc_wv      = (const float*)d_in[13];
    float* out = (float*)d_out;

    // workspace layout
    unsigned short* y_pk  = (unsigned short*)d_ws;            // 5,120,000 us
    float* accS = (float*)(y_pk + (size_t)5120000);           // 2,560,000 f32
    float* accV = accS + (size_t)2560000;                     // 7,680,000 f32
    unsigned short* xvP16 = (unsigned short*)(accV + (size_t)7680000);  // 3,840,000 us
    unsigned short* w_pk  = xvP16 + (size_t)3840000;          // 81,920,000 us
    int* deg       = (int*)(w_pk + (size_t)81920000);
    int* row_start = deg + 10016;
    int* cursor    = row_start + 10016;
    int* edge_list = cursor + 10016;
    int* srcs      = edge_list + N_EDGES;
    int* dsts      = srcs + N_EDGES;
    float* ea_sorted = (float*)(dsts + N_EDGES);
    unsigned short* b_pre = (unsigned short*)(ea_sorted + (size_t)N_EDGES * 4);
    unsigned short* w2a   = b_pre + (size_t)2 * 24576 * 8;
    unsigned short* w1a   = w2a + (size_t)4096 * 8;
    unsigned short* b_lin = w1a + (size_t)512 * 8;
    const size_t need = (size_t)5120000 * 2 + (size_t)(2560000 + 7680000) * 4
                      + (size_t)3840000 * 2 + (size_t)81920000 * 2
                      + (size_t)(10016 * 3 + N_EDGES * 3) * 4
                      + (size_t)N_EDGES * 4 * 4
                      + ((size_t)2 * 24576 * 8 + (size_t)4096 * 8 + (size_t)512 * 8
                         + (size_t)4096 * 8) * 2;
    if (ws_size < need) return;

    hipLaunchKernelGGL(pack_all_kernel, dim3(226), dim3(256), 0, stream,
                       sc_ws, lin2_ws, sc_wv, lin2_wv, fc_w2, fc_w1, lin1_ws, lin1_wv,
                       b_pre, w2a, w1a, b_lin);
    hipLaunchKernelGGL(node_lin1_mfma, dim3(313), dim3(256), 0, stream,
                       node_feats, b_lin, y_pk, xvP16);

    hipMemsetAsync(deg, 0, (size_t)N_NODES * sizeof(int), stream);
    hipLaunchKernelGGL(hist_kernel, dim3(625), dim3(256), 0, stream, edge_index, deg);
    hipLaunchKernelGGL(scan_kernel, dim3(1), dim3(1024), 0, stream, deg, row_start, cursor);
    hipLaunchKernelGGL(scatter_kernel, dim3(625), dim3(256), 0, stream,
                       edge_index, edge_attrs, cursor, edge_list, srcs, dsts, ea_sorted);
    hipLaunchKernelGGL(edge_w_mfma, dim3(2500), dim3(256), 0, stream,
                       edge_feats, edge_list, fc_w0, w1a, w2a, w_pk);
    hipLaunchKernelGGL(gather_kernel, dim3(1250), dim3(256), 0, stream,
                       row_start, srcs, dsts, ea_sorted, w_pk, y_pk, accS, accV);

    hipLaunchKernelGGL(node_out_mfma, dim3(SO_BLK + VO_BLK), dim3(256), 0, stream,
                       node_feats, node_attrs, xvP16, accS, accV, b_pre, out);
}

// Round 5
// 282.944 us; speedup vs baseline: 1.0241x; 1.0241x over previous
//
#include <hip/hip_runtime.h>
#include <hip/hip_bf16.h>
#include <math.h>

#define N_NODES 10000
#define N_EDGES 160000
#define SO_BLK 157          // ceil(10000/64) s-GEMM blocks
#define VO_BLK 469          // ceil(30000/64) v-GEMM blocks

typedef __attribute__((ext_vector_type(8))) short short8x;
typedef __attribute__((ext_vector_type(4))) float floatx4;
typedef __attribute__((ext_vector_type(4))) unsigned int uint4x;
typedef __attribute__((ext_vector_type(2))) unsigned int uint2x;

union S8 { short8x v; unsigned short u[8]; uint4 q; uint4x qx; };
union U2 { uint2x v; unsigned short us[4]; };

__device__ __forceinline__ unsigned short f2bf(float x) {
    unsigned int u = __float_as_uint(x);
    return (unsigned short)((u + 0x7fffu + ((u >> 16) & 1u)) >> 16);
}
__device__ __forceinline__ float bf2f(unsigned short u) {
    return __uint_as_float(((unsigned)u) << 16);
}
__device__ __forceinline__ float silu_c(float x) {
    return 1.679f * x / (1.0f + __expf(-x));
}

// ---------------- pack_all: all weight pre-packs in one launch ----------------
// blocks [0,192): b_pre; [192,208): w2a; [208,210): w1a; [210,226): b_lin
__global__ __launch_bounds__(256) void pack_all_kernel(
    const float* __restrict__ sc_ws, const float* __restrict__ lin2_ws,
    const float* __restrict__ sc_wv, const float* __restrict__ lin2_wv,
    const float* __restrict__ fc_w2, const float* __restrict__ fc_w1,
    const float* __restrict__ lin1_ws, const float* __restrict__ lin1_wv,
    unsigned short* __restrict__ b_pre, unsigned short* __restrict__ w2a,
    unsigned short* __restrict__ w1a, unsigned short* __restrict__ b_lin)
{
    const int bid = blockIdx.x;
    const int t = threadIdx.x;
    if (bid < 192) {
        int id = bid * 256 + t;                  // 0..49151
        int mat = id / 24576;
        int slot = id - mat * 24576;
        int ks = slot >> 9;
        int rr = slot & 511;
        int lane = rr & 63;
        int quad = lane >> 4;
        int n = ((rr >> 6) << 4) + (lane & 15);
        const float* sc  = mat ? sc_wv  : sc_ws;
        const float* lin = mat ? lin2_wv : lin2_ws;
        S8 pk;
        #pragma unroll
        for (int j = 0; j < 8; j++) {
            int k = ks * 32 + quad * 8 + j;
            float w;
            if (k < 1280) {
                int u = k & 127, v = k >> 7;
                w = sc[(u * 10 + v) * 128 + n];
            } else {
                w = lin[(k - 1280) * 128 + n];
            }
            pk.u[j] = f2bf(w);
        }
        *(uint4*)(b_pre + (size_t)id * 8) = pk.q;
    } else if (bid < 208) {
        int id = (bid - 192) * 256 + t;          // 0..4095
        int lane = id & 63;
        int mfg = (id >> 6) & 31;
        int ks = id >> 11;
        int col = mfg * 16 + (lane & 15);
        int k0 = ks * 32 + (lane >> 4) * 8;
        S8 pk;
        #pragma unroll
        for (int j = 0; j < 8; j++)
            pk.u[j] = f2bf(fc_w2[(k0 + j) * 512 + col] * 0.125f);
        *(uint4*)(w2a + (size_t)id * 8) = pk.q;
    } else if (bid < 210) {
        int id = (bid - 208) * 256 + t;          // 0..511
        int lane = id & 63;
        int mf = (id >> 6) & 3;
        int ks = id >> 8;
        int m = mf * 16 + (lane & 15);
        int k0 = ks * 32 + (lane >> 4) * 8;
        S8 pk;
        #pragma unroll
        for (int j = 0; j < 8; j++)
            pk.u[j] = f2bf(fc_w1[(k0 + j) * 64 + m] * 0.125f);
        *(uint4*)(w1a + (size_t)id * 8) = pk.q;
    } else {
        int id = (bid - 210) * 256 + t;          // 0..4095
        int mat = id >> 11;
        int slot = id & 2047;
        int ks = slot >> 9;
        int rr = slot & 511;
        int nf = rr >> 6;
        int lane = rr & 63;
        int n = nf * 16 + (lane & 15);
        int k0 = ks * 32 + (lane >> 4) * 8;
        const float* w = mat ? lin1_wv : lin1_ws;
        const float l1 = 0.0883883476483f;
        S8 pk;
        #pragma unroll
        for (int j = 0; j < 8; j++)
            pk.u[j] = f2bf(w[(k0 + j) * 128 + n] * l1);
        *(uint4*)(b_lin + (size_t)id * 8) = pk.q;
    }
}

// ---------------- Kernel A: lin1 via MFMA -> packed bf16 y + bf16 xvP ----------------
__global__ __launch_bounds__(256) void node_lin1_mfma(
    const float* __restrict__ node_feats,
    const unsigned short* __restrict__ b_lin,
    unsigned short* __restrict__ y_pk,
    unsigned short* __restrict__ xvP16)
{
    __shared__ __align__(16) unsigned char smem[32768];
    short8x* Al = (short8x*)smem;
    unsigned short* Yt = (unsigned short*)smem;

    const int blk = blockIdx.x;   // 313
    const int t = threadIdx.x;
    const int base = blk * 32;
    const int lane = t & 63;
    const int wv = t >> 6;
    const int m15 = lane & 15;
    const int k0q = (lane >> 4) * 8;

    #pragma unroll
    for (int it = 0; it < 8; it++) {
        int g = wv * 8 + it;
        int af = g >> 2;
        int ks = g & 3;
        int m = af * 16 + m15;
        int comp = m >> 5;
        int nloc = m & 31;
        int node = base + nloc;
        int valid = (node < N_NODES);
        if (!valid) node = N_NODES - 1;
        int k0 = ks * 32 + k0q;
        const float* row = node_feats + (size_t)node * 512;
        S8 pk;
        if (comp == 0) {
            float4 a = *(const float4*)&row[k0];
            float4 b = *(const float4*)&row[k0 + 4];
            pk.u[0] = f2bf(a.x); pk.u[1] = f2bf(a.y); pk.u[2] = f2bf(a.z); pk.u[3] = f2bf(a.w);
            pk.u[4] = f2bf(b.x); pk.u[5] = f2bf(b.y); pk.u[6] = f2bf(b.z); pk.u[7] = f2bf(b.w);
        } else {
            int c = comp - 1;
            #pragma unroll
            for (int j = 0; j < 8; j++)
                pk.u[j] = f2bf(row[128 + (k0 + j) * 3 + c]);
            if (valid)
                *(uint4*)&xvP16[((size_t)node * 3 + c) * 128 + k0] = pk.q;
        }
        Al[(ks * 8 + af) * 64 + lane] = pk.v;
    }
    __syncthreads();

    floatx4 c[8][2];
    #pragma unroll
    for (int af = 0; af < 8; af++) {
        c[af][0] = (floatx4){0.f, 0.f, 0.f, 0.f};
        c[af][1] = (floatx4){0.f, 0.f, 0.f, 0.f};
    }

    const uint4* bq = (const uint4*)b_lin;
    #pragma unroll
    for (int ks = 0; ks < 4; ks++) {
        S8 bs0, bs1, bv0, bv1;
        bs0.q = bq[       ks*512 + (wv*2+0)*64 + lane];
        bs1.q = bq[       ks*512 + (wv*2+1)*64 + lane];
        bv0.q = bq[2048 + ks*512 + (wv*2+0)*64 + lane];
        bv1.q = bq[2048 + ks*512 + (wv*2+1)*64 + lane];
        #pragma unroll
        for (int af = 0; af < 8; af++) {
            short8x a = Al[(ks*8 + af)*64 + lane];
            if (af < 2) {
                c[af][0] = __builtin_amdgcn_mfma_f32_16x16x32_bf16(a, bs0.v, c[af][0], 0, 0, 0);
                c[af][1] = __builtin_amdgcn_mfma_f32_16x16x32_bf16(a, bs1.v, c[af][1], 0, 0, 0);
            } else {
                c[af][0] = __builtin_amdgcn_mfma_f32_16x16x32_bf16(a, bv0.v, c[af][0], 0, 0, 0);
                c[af][1] = __builtin_amdgcn_mfma_f32_16x16x32_bf16(a, bv1.v, c[af][1], 0, 0, 0);
            }
        }
    }
    __syncthreads();

    {
        const int rq = (lane >> 4) * 4;
        #pragma unroll
        for (int af = 0; af < 8; af++) {
            #pragma unroll
            for (int nf = 0; nf < 2; nf++) {
                int u = wv * 32 + nf * 16 + m15;
                #pragma unroll
                for (int i = 0; i < 4; i++) {
                    int m = af * 16 + rq + i;
                    int comp = m >> 5, nloc = m & 31;
                    Yt[(nloc * 128 + u) * 4 + comp] = f2bf(c[af][nf][i]);
                }
            }
        }
    }
    __syncthreads();
    {
        unsigned short* dst = y_pk + (size_t)base * 512;
        int nrem = N_NODES - base;
        #pragma unroll
        for (int it = 0; it < 8; it++) {
            int idx = it * 256 + t;
            if ((idx >> 6) < nrem)
                *(uint4*)(dst + (size_t)idx * 8) = *(const uint4*)&Yt[idx * 8];
        }
    }
}

// ---------------- CSR build ----------------
__global__ __launch_bounds__(256) void hist_kernel(const int* __restrict__ edge_index,
                                                   int* __restrict__ deg) {
    int e = blockIdx.x * 256 + threadIdx.x;
    if (e < N_EDGES) atomicAdd(&deg[edge_index[e]], 1);
}

__global__ __launch_bounds__(1024) void scan_kernel(const int* __restrict__ deg,
                                                    int* __restrict__ row_start,
                                                    int* __restrict__ cursor) {
    __shared__ int wsum[16];
    __shared__ int carry_s;
    const int t = threadIdx.x;
    const int lane = t & 63, w = t >> 6;
    if (t == 0) carry_s = 0;
    __syncthreads();
    for (int chunk = 0; chunk < 10; chunk++) {
        int idx = chunk * 1024 + t;
        int v = (idx < N_NODES) ? deg[idx] : 0;
        int x = v;
        #pragma unroll
        for (int off = 1; off < 64; off <<= 1) {
            int yv = __shfl_up(x, off, 64);
            if (lane >= off) x += yv;
        }
        if (lane == 63) wsum[w] = x;
        __syncthreads();
        int wpre = 0;
        for (int i = 0; i < w; i++) wpre += wsum[i];
        int incl = x + wpre + carry_s;
        int excl = incl - v;
        if (idx < N_NODES) { row_start[idx] = excl; cursor[idx] = excl; }
        __syncthreads();
        if (t == 1023) carry_s = incl;
        __syncthreads();
    }
    if (t == 0) row_start[N_NODES] = carry_s;
}

__global__ __launch_bounds__(256) void scatter_kernel(const int* __restrict__ edge_index,
                                                      const float* __restrict__ edge_attrs,
                                                      int* __restrict__ cursor,
                                                      int* __restrict__ edge_list,
                                                      int* __restrict__ srcs,
                                                      float* __restrict__ ea_sorted) {
    int e = blockIdx.x * 256 + threadIdx.x;
    if (e < N_EDGES) {
        int pos = atomicAdd(&cursor[edge_index[e]], 1);
        edge_list[pos] = e;
        srcs[pos] = edge_index[N_EDGES + e];
        float4 ea = *(const float4*)(edge_attrs + (size_t)e * 4);
        *(float4*)(ea_sorted + (size_t)pos * 4) = ea;
    }
}

// ---------------- Kernel B1: edge MLP (sorted order) -> packed bf16 w ----------------
// w_pk[pos][u][4] = bf16{ss, sv, vs, vv}
// LDS 26.4 KB -> 6 blocks/CU; phase 3 in 4 passes of 2 m-frags (32 acc VGPRs)
// w_pk stores are NORMAL (not nontemporal): 82 MB < 256 MB Infinity Cache, so
// the gather that immediately follows reads MALL-resident lines, not HBM.
__global__ __launch_bounds__(256) void edge_w_mfma(
    const float* __restrict__ edge_feats,
    const int* __restrict__ edge_list,
    const float* __restrict__ fc_w0,
    const unsigned short* __restrict__ w1a,
    const unsigned short* __restrict__ w2a,
    unsigned short* __restrict__ w_pk)
{
    __shared__ __align__(16) unsigned char smem[26368];
    float* ef = (float*)smem;                               // [0, 2304)
    unsigned short* h0b = (unsigned short*)(smem + 2304);   // [2304, 11520): 64 x 72
    unsigned short* T   = (unsigned short*)smem;            // [0, 16896): 64 x 132 (epilogue)
    unsigned short* h1b = (unsigned short*)(smem + 16896);  // [16896, 26112): 64 x 72
    int* eids = (int*)(smem + 26112);                       // [26112, 26368)

    const int blk = blockIdx.x;      // 2500
    const int t = threadIdx.x;
    const int eb0 = blk * 64;
    const int lane = t & 63;
    const int wv = t >> 6;
    const int quad = lane >> 4;
    const int m15 = lane & 15;

    if (t < 64) eids[t] = edge_list[eb0 + t];
    __syncthreads();

    #pragma unroll
    for (int r = 0; r < 2; r++) {
        int idx = r * 256 + t;
        int el = idx >> 3;
        int k = idx & 7;
        ef[el * 9 + k] = edge_feats[(size_t)eids[el] * 8 + k];
    }
    __syncthreads();

    // phase 1 (VALU, f32): h0 = silu_c(ef @ w0 / sqrt(8)) -> bf16
    {
        const int e_loc = t >> 2;
        const int c0 = (t & 3) * 16;
        float a0[16];
        #pragma unroll
        for (int i = 0; i < 16; i++) a0[i] = 0.f;
        const float* efr = &ef[e_loc * 9];
        #pragma unroll
        for (int k = 0; k < 8; k++) {
            float ek = efr[k];
            float w[16];
            #pragma unroll
            for (int q4 = 0; q4 < 4; q4++)
                *(float4*)&w[q4*4] = *(const float4*)&fc_w0[k*64 + c0 + q4*4];
            #pragma unroll
            for (int i = 0; i < 16; i++) a0[i] += ek * w[i];
        }
        const float is8 = 0.35355339059f;
        S8 p0, p1;
        #pragma unroll
        for (int i = 0; i < 8; i++) {
            p0.u[i] = f2bf(silu_c(a0[i] * is8));
            p1.u[i] = f2bf(silu_c(a0[8 + i] * is8));
        }
        *(uint4*)&h0b[e_loc * 72 + c0]     = p0.q;
        *(uint4*)&h0b[e_loc * 72 + c0 + 8] = p1.q;
    }
    __syncthreads();

    // phase 2 (MFMA): h1 = silu_c(h0 @ w1 / 8)
    {
        floatx4 c2[4];
        #pragma unroll
        for (int ee = 0; ee < 4; ee++) c2[ee] = (floatx4){0.f, 0.f, 0.f, 0.f};
        const uint4* w1aq = (const uint4*)w1a;
        #pragma unroll
        for (int ks = 0; ks < 2; ks++) {
            S8 afr;
            afr.q = w1aq[(ks*4 + wv)*64 + lane];
            #pragma unroll
            for (int ee = 0; ee < 4; ee++) {
                S8 bfr;
                bfr.q = *(const uint4*)&h0b[(ee*16 + m15) * 72 + ks*32 + quad*8];
                c2[ee] = __builtin_amdgcn_mfma_f32_16x16x32_bf16(afr.v, bfr.v, c2[ee], 0, 0, 0);
            }
        }
        #pragma unroll
        for (int ee = 0; ee < 4; ee++) {
            ushort4 pk = make_ushort4(f2bf(silu_c(c2[ee][0])), f2bf(silu_c(c2[ee][1])),
                                      f2bf(silu_c(c2[ee][2])), f2bf(silu_c(c2[ee][3])));
            *(ushort4*)&h1b[(ee*16 + m15) * 72 + wv*16 + quad*4] = pk;
        }
    }
    __syncthreads();

    // phase 3 (MFMA, 4 passes of 2 m-frags); pass p covers cols p*32..p*32+31 of comp wv
    const uint4* w2aq = (const uint4*)w2a;
    #pragma unroll 1
    for (int p = 0; p < 4; p++) {
        floatx4 c3[2][4];
        #pragma unroll
        for (int mf = 0; mf < 2; mf++)
            #pragma unroll
            for (int ee = 0; ee < 4; ee++)
                c3[mf][ee] = (floatx4){0.f, 0.f, 0.f, 0.f};

        #pragma unroll
        for (int ks = 0; ks < 2; ks++) {
            S8 bfr[4];
            #pragma unroll
            for (int ee = 0; ee < 4; ee++)
                bfr[ee].q = *(const uint4*)&h1b[(ee*16 + m15) * 72 + ks*32 + quad*8];
            #pragma unroll
            for (int mf = 0; mf < 2; mf++) {
                S8 afr;
                afr.q = w2aq[(size_t)(ks*32 + wv*8 + p*2 + mf) * 64 + lane];
                #pragma unroll
                for (int ee = 0; ee < 4; ee++)
                    c3[mf][ee] = __builtin_amdgcn_mfma_f32_16x16x32_bf16(afr.v, bfr[ee].v, c3[mf][ee], 0, 0, 0);
            }
        }

        __syncthreads();   // T region free (prev pass stores done / ef+h0b dead)
        // dump interleaved: T[e*132 + col'*4 + comp], comp = wv
        #pragma unroll
        for (int mf = 0; mf < 2; mf++) {
            #pragma unroll
            for (int ee = 0; ee < 4; ee++) {
                int e = ee*16 + m15;
                #pragma unroll
                for (int i = 0; i < 4; i++) {
                    int colp = mf*16 + quad*4 + i;
                    T[e*132 + colp*4 + wv] = f2bf(c3[mf][ee][i]);
                }
            }
        }
        __syncthreads();

        // coalesced store: uint2 per (e, cu); per e-row 256 B contiguous
        #pragma unroll
        for (int it = 0; it < 8; it++) {
            int idx = it * 256 + t;          // 0..2047
            int e  = idx >> 5;
            int cu = idx & 31;
            uint2x v = *(const uint2x*)&T[e*132 + cu*4];
            unsigned short* dstp = w_pk + ((size_t)(eb0 + e) * 128 + p*32 + cu) * 4;
            *(uint2x*)dstp = v;            // normal store -> MALL-allocating
        }
    }
}

// ---------------- Kernel B2: wave-per-node gather ----------------
// One 64-lane wave per node (grid 2500 x 4 waves = 10000 waves, 32/CU cap).
// Lane owns 2 u-slots -> 16 B/lane dwordx4 for w and y (1 KB row per wave op).
// Depth-2 branch-free edge pipeline + depth-4 scalar srcs lookahead. Waves
// fully independent: no LDS, no syncthreads, direct epilogue store.
__global__ __launch_bounds__(256) void gather_kernel(
    const int* __restrict__ row_start,
    const int* __restrict__ srcs,
    const float* __restrict__ ea_sorted,
    const unsigned short* __restrict__ w_pk,
    const unsigned short* __restrict__ y_pk,
    float* __restrict__ accS,
    float* __restrict__ accV)
{
    const int t = threadIdx.x;
    const int n = blockIdx.x * 4 + (t >> 6);   // wave-per-node, grid 2500
    const int lane = t & 63;
    const int u0 = lane << 1;                  // u0, u0+1

    const int eb = row_start[n];
    const int ee = row_start[n + 1];

    float aS0a=0.f,aS0b=0.f, aS1a=0.f,aS1b=0.f;
    float aV2ax=0.f,aV2ay=0.f,aV2az=0.f, aV2bx=0.f,aV2by=0.f,aV2bz=0.f;
    float aV3ax=0.f,aV3ay=0.f,aV3az=0.f, aV3bx=0.f,aV3by=0.f,aV3bz=0.f;

    auto consume = [&](const S8& w8, const S8& y8, const float4& ea) {
        // u0 slot
        {
            float wss = bf2f(w8.u[0]), wsv = bf2f(w8.u[1]);
            float wvs = bf2f(w8.u[2]), wvv = bf2f(w8.u[3]);
            float qs = bf2f(y8.u[0]), q0 = bf2f(y8.u[1]), q1 = bf2f(y8.u[2]), q2 = bf2f(y8.u[3]);
            aS0a += wss * qs * ea.x;
            aS1a += wvv * (q0*ea.y + q1*ea.z + q2*ea.w);
            float tsv = wsv * qs;
            aV2ax += tsv * ea.y; aV2ay += tsv * ea.z; aV2az += tsv * ea.w;
            float tvs = wvs * ea.x;
            aV3ax += tvs * q0; aV3ay += tvs * q1; aV3az += tvs * q2;
        }
        // u0+1 slot
        {
            float wss = bf2f(w8.u[4]), wsv = bf2f(w8.u[5]);
            float wvs = bf2f(w8.u[6]), wvv = bf2f(w8.u[7]);
            float qs = bf2f(y8.u[4]), q0 = bf2f(y8.u[5]), q1 = bf2f(y8.u[6]), q2 = bf2f(y8.u[7]);
            aS0b += wss * qs * ea.x;
            aS1b += wvv * (q0*ea.y + q1*ea.z + q2*ea.w);
            float tsv = wsv * qs;
            aV2bx += tsv * ea.y; aV2by += tsv * ea.z; aV2bz += tsv * ea.w;
            float tvs = wvs * ea.x;
            aV3bx += tvs * q0; aV3by += tvs * q1; aV3bz += tvs * q2;
        }
    };

    if (eb < ee) {
        const int lastE = ee - 1;
        int j1 = (eb+1 < lastE) ? eb+1 : lastE;
        int sA = srcs[eb];
        int sB = srcs[j1];
        int sP0 = srcs[(eb+2 < lastE) ? eb+2 : lastE];
        int sP1 = srcs[(eb+3 < lastE) ? eb+3 : lastE];

        S8 wA, wB, yA, yB; float4 eaA, eaB;
        wA.qx = __builtin_nontemporal_load((const uint4x*)(w_pk + ((size_t)eb * 128 + u0) * 4));
        eaA   = *(const float4*)(ea_sorted + (size_t)eb * 4);
        yA.q  = *(const uint4*)(y_pk + ((size_t)sA * 128 + u0) * 4);
        wB.qx = __builtin_nontemporal_load((const uint4x*)(w_pk + ((size_t)j1 * 128 + u0) * 4));
        eaB   = *(const float4*)(ea_sorted + (size_t)j1 * 4);
        yB.q  = *(const uint4*)(y_pk + ((size_t)sB * 128 + u0) * 4);

        for (int i = eb; i < ee; i += 2) {
            // ---- consume A (edge i, always valid) ----
            consume(wA, yA, eaA);
            // ---- refill A <- edge i+2 (clamped within node; never consumed if invalid) ----
            {
                int jn = (i+2 < lastE) ? i+2 : lastE;
                wA.qx = __builtin_nontemporal_load((const uint4x*)(w_pk + ((size_t)jn * 128 + u0) * 4));
                eaA   = *(const float4*)(ea_sorted + (size_t)jn * 4);
                yA.q  = *(const uint4*)(y_pk + ((size_t)sP0 * 128 + u0) * 4);
                sP0 = srcs[(i+4 < lastE) ? i+4 : lastE];
            }
            // ---- consume B (edge i+1; wave-uniform guard) ----
            if (i + 1 < ee) consume(wB, yB, eaB);
            // ---- refill B <- edge i+3 (clamped) ----
            {
                int jn = (i+3 < lastE) ? i+3 : lastE;
                wB.qx = __builtin_nontemporal_load((const uint4x*)(w_pk + ((size_t)jn * 128 + u0) * 4));
                eaB   = *(const float4*)(ea_sorted + (size_t)jn * 4);
                yB.q  = *(const uint4*)(y_pk + ((size_t)sP1 * 128 + u0) * 4);
                sP1 = srcs[(i+5 < lastE) ? i+5 : lastE];
            }
        }
    }

    const float inv = 0.25f;                   // 1/sqrt(16)
    const float s1c = 0.57735026919f * 0.25f;
    *(float2*)(accS + (size_t)n*256 + u0)        = make_float2(aS0a*inv, aS0b*inv);
    *(float2*)(accS + (size_t)n*256 + 128 + u0)  = make_float2(aS1a*s1c, aS1b*s1c);
    *(float2*)(accV + ((size_t)n*3+0)*256 + u0)       = make_float2(aV2ax*inv, aV2bx*inv);
    *(float2*)(accV + ((size_t)n*3+0)*256 + 128 + u0) = make_float2(aV3ax*inv, aV3bx*inv);
    *(float2*)(accV + ((size_t)n*3+1)*256 + u0)       = make_float2(aV2ay*inv, aV2by*inv);
    *(float2*)(accV + ((size_t)n*3+1)*256 + 128 + u0) = make_float2(aV3ay*inv, aV3by*inv);
    *(float2*)(accV + ((size_t)n*3+2)*256 + u0)       = make_float2(aV2az*inv, aV2bz*inv);
    *(float2*)(accV + ((size_t)n*3+2)*256 + 128 + u0) = make_float2(aV3az*inv, aV3bz*inv);
}

// ---------------- node_out as MFMA GEMM, latency-pipelined ----------------
// 64-row tiles (grid 626 = 2.45 blocks/CU), one A-slot per thread (conflict-free
// LDS), sc-part A preloaded in registers (4 chunks x 8), depth-2 B / tail-acc
// register prefetch, one raw s_barrier per K-step (lgkmcnt-only drain so B
// prefetch stays in flight across barriers).
__global__ __launch_bounds__(256) void node_out_mfma(
    const float* __restrict__ node_feats,
    const float* __restrict__ node_attrs,
    const unsigned short* __restrict__ xvP16,
    const float* __restrict__ accS,
    const float* __restrict__ accV,
    const unsigned short* __restrict__ b_pre,
    float* __restrict__ out)
{
    __shared__ __align__(16) short8x Abuf[2][256];   // 2 x 4 KB double buffer
    const int bid = blockIdx.x;
    const int t = threadIdx.x;
    const int lane = t & 63;
    const int wv = t >> 6;
    const bool is_s = (bid < SO_BLK);

    // this thread's A slot: row r (0..63), k-quad (0..3); slot index == t
    const int r    = ((t >> 6) << 4) + (t & 15);
    const int q8   = ((t >> 4) & 3) * 8;

    const float* px = nullptr;
    const unsigned short* pxv = nullptr;
    const float* pa;
    const float* pat;
    if (is_s) {
        int R = bid * 64 + r;
        int node = (R < N_NODES) ? R : 0;
        px  = node_feats + (size_t)node * 512;
        pa  = accS + (size_t)node * 256;
        pat = node_attrs + node * 10;
    } else {
        int Rg = (bid - SO_BLK) * 64 + r;
        if (Rg >= 3 * N_NODES) Rg = 0;
        int node = Rg / 3;
        pxv = xvP16 + (size_t)Rg * 128;
        pa  = accV + (size_t)Rg * 256;
        pat = node_attrs + node * 10;
    }

    const uint4* bb = (const uint4*)(b_pre) + (is_s ? 0 : 24576);
    const float sc_norm = 0.02795084972f;   // 1/sqrt(1280)
    const float l2 = 0.0625f;               // 1/sqrt(256)

    // ---- preload the 4 sc-part A chunks for this (row, quad) ----
    float xf[4][8];
    S8    xh[4];
    if (is_s) {
        #pragma unroll
        for (int c = 0; c < 4; c++) {
            floatx4 lo = *(const floatx4*)&px[c*32 + q8];
            floatx4 hi = *(const floatx4*)&px[c*32 + q8 + 4];
            #pragma unroll
            for (int i = 0; i < 4; i++) { xf[c][i] = lo[i]; xf[c][4+i] = hi[i]; }
        }
    } else {
        #pragma unroll
        for (int c = 0; c < 4; c++)
            xh[c].q = *(const uint4*)&pxv[c*32 + q8];
    }
    float attC = pat[0] * sc_norm;

    floatx4 acc[4][2];
    #pragma unroll
    for (int af = 0; af < 4; af++) {
        acc[af][0] = (floatx4){0.f, 0.f, 0.f, 0.f};
        acc[af][1] = (floatx4){0.f, 0.f, 0.f, 0.f};
    }

    const int cof0 = (wv*2+0)*64 + lane;
    const int cof1 = (wv*2+1)*64 + lane;

    auto packx = [&](int c_, float att_) -> short8x {
        S8 pk;
        if (is_s) {
            #pragma unroll
            for (int i = 0; i < 8; i++) pk.u[i] = f2bf(xf[c_][i] * att_);
        } else {
            #pragma unroll
            for (int i = 0; i < 8; i++) pk.u[i] = f2bf(bf2f(xh[c_].u[i]) * att_);
        }
        return pk.v;
    };
    auto mstep = [&](int kb, const S8& b0, const S8& b1) {
        __builtin_amdgcn_s_setprio(1);
        #pragma unroll
        for (int af = 0; af < 4; af++) {
            short8x a = Abuf[kb][af*64 + lane];
            acc[af][0] = __builtin_amdgcn_mfma_f32_16x16x32_bf16(a, b0.v, acc[af][0], 0, 0, 0);
            acc[af][1] = __builtin_amdgcn_mfma_f32_16x16x32_bf16(a, b1.v, acc[af][1], 0, 0, 0);
        }
        __builtin_amdgcn_s_setprio(0);
    };
    auto bload = [&](int k2, S8& b0, S8& b1) {
        b0.q = bb[(size_t)k2*512 + cof0];
        b1.q = bb[(size_t)k2*512 + cof1];
    };
    auto barrier_ = [&]() {
        asm volatile("s_waitcnt lgkmcnt(0)" ::: "memory");
        __builtin_amdgcn_s_barrier();
    };

    // B prefetch (depth 2)
    S8 bA0, bA1, bB0, bB1;
    bload(0, bA0, bA1);
    bload(1, bB0, bB1);

    // prologue: A(0) -> buf0
    Abuf[0][t] = packx(0, attC);
    barrier_();

    // ---- main loop: ks = 0..35 (vblk 0..8), A from preloaded chunks ----
    #pragma unroll 1
    for (int vb = 0; vb < 9; vb++) {
        float attN = pat[vb + 1] * sc_norm;
        const int ksb = vb * 4;
        Abuf[1][t] = packx(1, attC); mstep(0, bA0, bA1); bload(ksb+2, bA0, bA1); barrier_();
        Abuf[0][t] = packx(2, attC); mstep(1, bB0, bB1); bload(ksb+3, bB0, bB1); barrier_();
        Abuf[1][t] = packx(3, attC); mstep(0, bA0, bA1); bload(ksb+4, bA0, bA1); barrier_();
        Abuf[0][t] = packx(0, attN); mstep(1, bB0, bB1); bload(ksb+5, bB0, bB1); barrier_();
        attC = attN;
    }

    // ---- ks = 36..47 explicit (attC == pat[9]); tail A from acc (depth-2) ----
    floatx4 aT0[2], aT1[2];
    auto issue0 = [&](int k_) { int j2 = (k_-40)*32 + q8;
        aT0[0] = *(const floatx4*)&pa[j2]; aT0[1] = *(const floatx4*)&pa[j2+4]; };
    auto issue1 = [&](int k_) { int j2 = (k_-40)*32 + q8;
        aT1[0] = *(const floatx4*)&pa[j2]; aT1[1] = *(const floatx4*)&pa[j2+4]; };
    auto packT = [&](const floatx4* a2) -> short8x {
        S8 pk;
        #pragma unroll
        for (int i = 0; i < 4; i++) { pk.u[i] = f2bf(a2[0][i] * l2); pk.u[4+i] = f2bf(a2[1][i] * l2); }
        return pk.v;
    };

    // ks=36
    Abuf[1][t] = packx(1, attC); mstep(0, bA0, bA1); bload(38, bA0, bA1); barrier_();
    // ks=37
    Abuf[0][t] = packx(2, attC); mstep(1, bB0, bB1); bload(39, bB0, bB1); barrier_();
    // ks=38
    issue0(40);
    Abuf[1][t] = packx(3, attC); mstep(0, bA0, bA1); bload(40, bA0, bA1); barrier_();
    // ks=39
    issue1(41);
    Abuf[0][t] = packT(aT0); mstep(1, bB0, bB1); bload(41, bB0, bB1); barrier_();
    // ks=40
    issue0(42);
    Abuf[1][t] = packT(aT1); mstep(0, bA0, bA1); bload(42, bA0, bA1); barrier_();
    // ks=41
    issue1(43);
    Abuf[0][t] = packT(aT0); mstep(1, bB0, bB1); bload(43, bB0, bB1); barrier_();
    // ks=42
    issue0(44);
    Abuf[1][t] = packT(aT1); mstep(0, bA0, bA1); bload(44, bA0, bA1); barrier_();
    // ks=43
    issue1(45);
    Abuf[0][t] = packT(aT0); mstep(1, bB0, bB1); bload(45, bB0, bB1); barrier_();
    // ks=44
    issue0(46);
    Abuf[1][t] = packT(aT1); mstep(0, bA0, bA1); bload(46, bA0, bA1); barrier_();
    // ks=45
    issue1(47);
    Abuf[0][t] = packT(aT0); mstep(1, bB0, bB1); bload(47, bB0, bB1); barrier_();
    // ks=46
    Abuf[1][t] = packT(aT1); mstep(0, bA0, bA1); barrier_();
    // ks=47
    mstep(1, bB0, bB1);

    // ---- epilogue ----
    const int m = lane & 15;
    const int rq = (lane >> 4) * 4;
    if (is_s) {
        const int n0 = bid * 64;
        #pragma unroll
        for (int af = 0; af < 4; af++) {
            #pragma unroll
            for (int i = 0; i < 4; i++) {
                int n = n0 + af*16 + rq + i;
                if (n < N_NODES) {
                    out[(size_t)n*512 + wv*32 + m]      = acc[af][0][i];
                    out[(size_t)n*512 + wv*32 + 16 + m] = acc[af][1][i];
                }
            }
        }
    } else {
        const int r0 = (bid - SO_BLK) * 64;
        #pragma unroll
        for (int af = 0; af < 4; af++) {
            #pragma unroll
            for (int i = 0; i < 4; i++) {
                int Rg = r0 + af*16 + rq + i;
                if (Rg < 3 * N_NODES) {
                    int nn = Rg / 3;
                    int cc = Rg - nn * 3;
                    float* po = out + (size_t)nn*512 + 128 + cc;
                    po[(wv*32 + m)*3]      = acc[af][0][i];
                    po[(wv*32 + 16 + m)*3] = acc[af][1][i];
                }
            }
        }
    }
}

extern "C" void kernel_launch(void* const* d_in, const int* in_sizes, int n_in,
                              void* d_out, int out_size, void* d_ws, size_t ws_size,
                              hipStream_t stream) {
    const float* node_feats = (const float*)d_in[0];
    const float* node_attrs = (const float*)d_in[1];
    const float* edge_feats = (const float*)d_in[2];
    const float* edge_attrs = (const float*)d_in[3];
    const int*   edge_index = (const int*)  d_in[4];
    const float* lin1_ws    = (const float*)d_in[5];
    const float* lin1_wv    = (const float*)d_in[6];
    const float* fc_w0      = (const float*)d_in[7];
    const float* fc_w1      = (const float*)d_in[8];
    const float* fc_w2      = (const float*)d_in[9];
    const float* lin2_ws    = (const float*)d_in[10];
    const float* lin2_wv    = (const float*)d_in[11];
    const float* sc_ws      = (const float*)d_in[12];
    const float* sc_wv      = (const float*)d_in[13];
    float* out = (float*)d_out;

    // workspace layout
    unsigned short* y_pk  = (unsigned short*)d_ws;            // 5,120,000 us
    float* accS = (float*)(y_pk + (size_t)5120000);           // 2,560,000 f32
    float* accV = accS + (size_t)2560000;                     // 7,680,000 f32
    unsigned short* xvP16 = (unsigned short*)(accV + (size_t)7680000);  // 3,840,000 us
    unsigned short* w_pk  = xvP16 + (size_t)3840000;          // 81,920,000 us
    int* deg       = (int*)(w_pk + (size_t)81920000);
    int* row_start = deg + 10016;
    int* cursor    = row_start + 10016;
    int* edge_list = cursor + 10016;
    int* srcs      = edge_list + N_EDGES;
    float* ea_sorted = (float*)(srcs + N_EDGES);
    unsigned short* b_pre = (unsigned short*)(ea_sorted + (size_t)N_EDGES * 4);
    unsigned short* w2a   = b_pre + (size_t)2 * 24576 * 8;
    unsigned short* w1a   = w2a + (size_t)4096 * 8;
    unsigned short* b_lin = w1a + (size_t)512 * 8;
    const size_t need = (size_t)5120000 * 2 + (size_t)(2560000 + 7680000) * 4
                      + (size_t)3840000 * 2 + (size_t)81920000 * 2
                      + (size_t)(10016 * 3 + N_EDGES * 2) * 4
                      + (size_t)N_EDGES * 4 * 4
                      + ((size_t)2 * 24576 * 8 + (size_t)4096 * 8 + (size_t)512 * 8
                         + (size_t)4096 * 8) * 2;
    if (ws_size < need) return;

    hipLaunchKernelGGL(pack_all_kernel, dim3(226), dim3(256), 0, stream,
                       sc_ws, lin2_ws, sc_wv, lin2_wv, fc_w2, fc_w1, lin1_ws, lin1_wv,
                       b_pre, w2a, w1a, b_lin);
    hipLaunchKernelGGL(node_lin1_mfma, dim3(313), dim3(256), 0, stream,
                       node_feats, b_lin, y_pk, xvP16);

    hipMemsetAsync(deg, 0, (size_t)N_NODES * sizeof(int), stream);
    hipLaunchKernelGGL(hist_kernel, dim3(625), dim3(256), 0, stream, edge_index, deg);
    hipLaunchKernelGGL(scan_kernel, dim3(1), dim3(1024), 0, stream, deg, row_start, cursor);
    hipLaunchKernelGGL(scatter_kernel, dim3(625), dim3(256), 0, stream,
                       edge_index, edge_attrs, cursor, edge_list, srcs, ea_sorted);
    hipLaunchKernelGGL(edge_w_mfma, dim3(2500), dim3(256), 0, stream,
                       edge_feats, edge_list, fc_w0, w1a, w2a, w_pk);
    hipLaunchKernelGGL(gather_kernel, dim3(2500), dim3(256), 0, stream,
                       row_start, srcs, ea_sorted, w_pk, y_pk, accS, accV);

    hipLaunchKernelGGL(node_out_mfma, dim3(SO_BLK + VO_BLK), dim3(256), 0, stream,
                       node_feats, node_attrs, xvP16, accS, accV, b_pre, out);
}